// Round 3
// baseline (477.635 us; speedup 1.0000x reference)
//
#include <hip/hip_runtime.h>
#include <math.h>

typedef __attribute__((ext_vector_type(8))) short short8;
typedef __attribute__((ext_vector_type(4))) float float4v;

#define NLAGS 9
#define HID 256
#define GSAMP 16
#define MROWS 144          // GSAMP * NLAGS
#define STR 264            // LDS row stride (bf16 elems); rows 16B-aligned
#define F32STR 260         // f32 row stride for final l3 buffer
#define NTHREADS 512
#define PAD_OFF (2 * MROWS * STR)                   // sPad offset in shorts
#define SBUF_SHORTS (2 * MROWS * STR + MROWS * 32)  // 80,640 shorts = 161,280 B

union S8 { short8 v; unsigned short u[8]; };

__device__ __forceinline__ float b2f(unsigned short u) {
  union { unsigned int i; float f; } c; c.i = ((unsigned int)u) << 16; return c.f;
}
__device__ __forceinline__ unsigned short f2b(float f) {
  union { float f; unsigned int i; } c; c.f = f;
  return (unsigned short)((c.i + 0x7FFFu + ((c.i >> 16) & 1u)) >> 16);  // RNE
}
__device__ __forceinline__ float sane(float x) {
  // squash NaN/Inf/huge to 0 — converts any dtype-misread into finite signal
  return (__builtin_isfinite(x) && fabsf(x) < 1e30f) ? x : 0.0f;
}
__device__ __forceinline__ float ftanh(float x) {
  x = fminf(fmaxf(x, -9.0f), 9.0f);
  float t = __expf(2.0f * x);
  return 1.0f - 2.0f * __builtin_amdgcn_rcpf(t + 1.0f);
}
__device__ __forceinline__ float4v mfma16(short8 a, short8 b, float4v c) {
  return __builtin_amdgcn_mfma_f32_16x16x32_bf16(a, b, c, 0, 0, 0);
}

// ---- prep: f32 weights -> transposed bf16 copies in ws ----
// layout (bf16 elems): Wl2t[256][256] @0, Ww2t @65536, Wm1t[256][512] @131072,
//                      Wm2t[256][512] @262144, Ww1p[256][32] @393216 (K padded 8->32)
__global__ void prep_kernel(const float* __restrict__ Wl2,
                            const float* __restrict__ Ww2,
                            const float* __restrict__ Wm1,
                            const float* __restrict__ Wm2,
                            const float* __restrict__ Ww1,
                            unsigned short* __restrict__ ws)
{
  int idx = blockIdx.x * 256 + threadIdx.x;   // 0..401407
  if (idx < 65536) {
    int n = idx >> 8, k = idx & 255;
    ws[idx] = f2b(sane(Wl2[k * 256 + n]));
  } else if (idx < 131072) {
    int j = idx - 65536; int n = j >> 8, k = j & 255;
    ws[idx] = f2b(sane(Ww2[k * 256 + n]));
  } else if (idx < 262144) {
    int j = idx - 131072; int n = j >> 9, k = j & 511;
    ws[idx] = f2b(sane(Wm1[k * 256 + n]));
  } else if (idx < 393216) {
    int j = idx - 262144; int n = j >> 9, k = j & 511;
    ws[idx] = f2b(sane(Wm2[k * 256 + n]));
  } else if (idx < 401408) {
    int j = idx - 393216; int n = j >> 5, k = j & 31;
    ws[idx] = (k < 8) ? f2b(sane(Ww1[k * 256 + n])) : (unsigned short)0;
  }
}

__global__ void __launch_bounds__(NTHREADS, 2)
fused_kernel(const float* __restrict__ lags,
             const float* __restrict__ weather,
             const float* __restrict__ Wl1,
             const float* __restrict__ bl1,
             const float* __restrict__ gbn,
             const float* __restrict__ bbn,
             const float* __restrict__ bl2,
             const float* __restrict__ bw1,
             const float* __restrict__ bw2,
             const float* __restrict__ bm1,
             const float* __restrict__ bm2,
             const float* __restrict__ Wreg,
             const float* __restrict__ breg,
             const unsigned short* __restrict__ ws,
             float* __restrict__ out)
{
  __shared__ __align__(16) unsigned short sBuf[SBUF_SHORTS];  // 161,280 B
  unsigned short* sL = sBuf;
  unsigned short* sW = sBuf + MROWS * STR;
  unsigned short* sPad = sBuf + PAD_OFF;       // 144 x 32 padded weather (bf16)

  const int tid = threadIdx.x;
  const int wave = tid >> 6;
  const int lane16 = tid & 15;
  const int g4 = (tid >> 4) & 3;
  const int s0 = blockIdx.x * GSAMP;

  const unsigned short* Wl2t = ws;
  const unsigned short* Ww2t = ws + 65536;
  const unsigned short* Wm1t = ws + 131072;
  const unsigned short* Wm2t = ws + 262144;
  const unsigned short* Ww1p = ws + 393216;

  const int c0 = wave * 32 + lane16;       // wave's two output columns
  const int c1 = wave * 32 + 16 + lane16;

  // ---- Zero-init ALL of LDS ----
  {
    short8 z = {0,0,0,0,0,0,0,0};
    #pragma unroll
    for (int i = 0; i < 20; ++i) {
      int c = tid + i * NTHREADS;
      if (c * 8 < SBUF_SHORTS) *(short8*)(sBuf + c * 8) = z;
    }
  }
  __syncthreads();

  // ---- Phase A: l0 = BN(tanh(lag * Wl1 + bl1)) -> sL (bf16); weather -> sPad ----
  {
    const float BNS = 0.99999500003750f;  // 1/sqrt(1+1e-5)
    #pragma unroll
    for (int i = 0; i < 9; ++i) {
      int c = tid + i * NTHREADS;       // 4608 chunks of 8 cols
      int row = c >> 5;                 // 0..143  (= sample*9 + lag)
      int h0 = (c & 31) << 3;           // 0..248
      float lag = sane(lags[s0 * NLAGS + row]);
      float4v w0 = *(const float4v*)(Wl1 + h0);
      float4v w1 = *(const float4v*)(Wl1 + h0 + 4);
      float4v a0 = *(const float4v*)(bl1 + h0);
      float4v a1 = *(const float4v*)(bl1 + h0 + 4);
      float4v g0 = *(const float4v*)(gbn + h0);
      float4v g1 = *(const float4v*)(gbn + h0 + 4);
      float4v q0 = *(const float4v*)(bbn + h0);
      float4v q1 = *(const float4v*)(bbn + h0 + 4);
      S8 o8;
      #pragma unroll
      for (int e = 0; e < 4; ++e) {
        float v = ftanh(fmaf(lag, sane(w0[e]), sane(a0[e])));
        o8.u[e] = f2b(fmaf(v, sane(g0[e]) * BNS, sane(q0[e])));
      }
      #pragma unroll
      for (int e = 0; e < 4; ++e) {
        float v = ftanh(fmaf(lag, sane(w1[e]), sane(a1[e])));
        o8.u[e + 4] = f2b(fmaf(v, sane(g1[e]) * BNS, sane(q1[e])));
      }
      *(short8*)(sL + row * STR + h0) = o8.v;
    }
    if (tid < MROWS) {
      float4v x0 = *(const float4v*)(weather + s0 * 72 + tid * 8);
      float4v x1 = *(const float4v*)(weather + s0 * 72 + tid * 8 + 4);
      S8 o8;
      #pragma unroll
      for (int e = 0; e < 4; ++e) { o8.u[e] = f2b(sane(x0[e])); o8.u[e + 4] = f2b(sane(x1[e])); }
      *(short8*)(sPad + tid * 32) = o8.v;  // cols 8..31 stay zero
    }
  }
  __syncthreads();

  // ---- Phase B: w0 = tanh(weatherPad @ Ww1 + bw1)  (K=32, sPad -> sW, disjoint) ----
  {
    float4v acc0[9], acc1[9];
    short8 bf0 = *(const short8*)(Ww1p + c0 * 32 + g4 * 8);
    short8 bf1 = *(const short8*)(Ww1p + c1 * 32 + g4 * 8);
    #pragma unroll
    for (int m = 0; m < 9; ++m) {
      short8 a = *(const short8*)(sPad + (m * 16 + lane16) * 32 + g4 * 8);
      float4v z = {0.f, 0.f, 0.f, 0.f};
      acc0[m] = mfma16(a, bf0, z);
      acc1[m] = mfma16(a, bf1, z);
    }
    float bia0 = sane(bw1[c0]), bia1 = sane(bw1[c1]);
    #pragma unroll
    for (int m = 0; m < 9; ++m) {
      #pragma unroll
      for (int i = 0; i < 4; ++i) {
        int row = m * 16 + g4 * 4 + i;   // C/D: col=lane&15, row=(lane>>4)*4+i
        sW[row * STR + c0] = f2b(ftanh(acc0[m][i] + bia0));
        sW[row * STR + c1] = f2b(ftanh(acc1[m][i] + bia1));
      }
    }
  }
  __syncthreads();

  // ---- in-place GEMM (K=256): X = tanh(X @ W + b) ----
  auto gemm256 = [&](unsigned short* Abuf, const unsigned short* Bt,
                     const float* bias) {
    float4v acc0[9], acc1[9];
    #pragma unroll
    for (int m = 0; m < 9; ++m) {
      float4v z = {0.f,0.f,0.f,0.f};
      acc0[m] = z; acc1[m] = z;
    }
    for (int kk = 0; kk < 8; ++kk) {
      short8 b0 = *(const short8*)(Bt + c0 * 256 + kk * 32 + g4 * 8);
      short8 b1 = *(const short8*)(Bt + c1 * 256 + kk * 32 + g4 * 8);
      #pragma unroll
      for (int m = 0; m < 9; ++m) {
        short8 a = *(const short8*)(Abuf + (m * 16 + lane16) * STR + kk * 32 + g4 * 8);
        acc0[m] = mfma16(a, b0, acc0[m]);
        acc1[m] = mfma16(a, b1, acc1[m]);
      }
    }
    __syncthreads();   // all waves' A reads complete before overwrite
    float bia0 = sane(bias[c0]), bia1 = sane(bias[c1]);
    #pragma unroll
    for (int m = 0; m < 9; ++m) {
      #pragma unroll
      for (int i = 0; i < 4; ++i) {
        int row = m * 16 + g4 * 4 + i;
        Abuf[row * STR + c0] = f2b(ftanh(acc0[m][i] + bia0));
        Abuf[row * STR + c1] = f2b(ftanh(acc1[m][i] + bia1));
      }
    }
    __syncthreads();
  };

  gemm256(sL, Wl2t, bl2);   // l1
  gemm256(sW, Ww2t, bw2);   // w1

  // ---- per-sample mean aggregation (fixed 9x9 adjacency), in-place, thread-local ----
  auto aggregate = [&](unsigned short* buf) {
    int s = tid >> 5;
    int h0 = (tid & 31) << 3;
    float v[9][8];
    #pragma unroll
    for (int r = 0; r < 9; ++r) {
      S8 x; x.v = *(const short8*)(buf + (s * NLAGS + r) * STR + h0);
      #pragma unroll
      for (int e = 0; e < 8; ++e) v[r][e] = b2f(x.u[e]);
    }
    S8 o[9];
    #pragma unroll
    for (int e = 0; e < 8; ++e) {
      o[0].u[e] = f2b(v[8][e]);
      o[1].u[e] = f2b(v[0][e]);
      o[2].u[e] = f2b((1.f/3.f)*v[0][e] + (2.f/3.f)*v[1][e]);
      o[3].u[e] = f2b(0.2f*v[0][e] + 0.4f*v[1][e] + 0.4f*v[2][e]);
      o[4].u[e] = f2b(0.2f*v[1][e] + 0.4f*v[2][e] + 0.4f*v[3][e]);
      o[5].u[e] = f2b(0.2f*v[2][e] + 0.4f*v[3][e] + 0.4f*v[4][e]);
      o[6].u[e] = f2b(0.2f*v[3][e] + 0.4f*v[4][e] + 0.4f*v[5][e]);
      o[7].u[e] = f2b(0.25f*v[4][e] + 0.5f*v[5][e] + 0.25f*v[6][e]);
      o[8].u[e] = f2b((1.f/3.f)*(v[5][e] + v[6][e] + v[7][e]));
    }
    #pragma unroll
    for (int r = 0; r < 9; ++r)
      *(short8*)(buf + (s * NLAGS + r) * STR + h0) = o[r].v;
  };

  aggregate(sL);            // ml1
  __syncthreads();
  aggregate(sW);            // mw1 (becomes w2)
  __syncthreads();

  // ---- merge GEMM (K=512 over concat(sL,sW)); linear (no tanh) ----
  auto merge = [&](const unsigned short* Bt, const float* bias, bool outf32) {
    float4v acc0[9], acc1[9];
    #pragma unroll
    for (int m = 0; m < 9; ++m) {
      float4v z = {0.f,0.f,0.f,0.f};
      acc0[m] = z; acc1[m] = z;
    }
    for (int kk = 0; kk < 16; ++kk) {
      const unsigned short* Ab = (kk < 8) ? sL : sW;
      int ko = (kk & 7) * 32;
      short8 b0 = *(const short8*)(Bt + c0 * 512 + kk * 32 + g4 * 8);
      short8 b1 = *(const short8*)(Bt + c1 * 512 + kk * 32 + g4 * 8);
      #pragma unroll
      for (int m = 0; m < 9; ++m) {
        short8 a = *(const short8*)(Ab + (m * 16 + lane16) * STR + ko + g4 * 8);
        acc0[m] = mfma16(a, b0, acc0[m]);
        acc1[m] = mfma16(a, b1, acc1[m]);
      }
    }
    __syncthreads();   // all A reads complete before any overwrite
    float bia0 = sane(bias[c0]), bia1 = sane(bias[c1]);
    if (!outf32) {
      #pragma unroll
      for (int m = 0; m < 9; ++m) {
        #pragma unroll
        for (int i = 0; i < 4; ++i) {
          int row = m * 16 + g4 * 4 + i;
          sL[row * STR + c0] = f2b(acc0[m][i] + bia0);
          sL[row * STR + c1] = f2b(acc1[m][i] + bia1);
        }
      }
    } else {
      float* f3 = (float*)sBuf;   // l3 kept f32 for the final dot
      #pragma unroll
      for (int m = 0; m < 9; ++m) {
        #pragma unroll
        for (int i = 0; i < 4; ++i) {
          int row = m * 16 + g4 * 4 + i;
          f3[row * F32STR + c0] = acc0[m][i] + bia0;
          f3[row * F32STR + c1] = acc1[m][i] + bia1;
        }
      }
    }
    __syncthreads();
  };

  merge(Wm1t, bm1, false);  // l2 -> sL ; sW still holds mw1 = w2
  aggregate(sL);            // ml2
  __syncthreads();
  aggregate(sW);            // mw2
  __syncthreads();
  merge(Wm2t, bm2, true);   // l3 -> f32 over sBuf (143*260+255 floats fits)

  // ---- final regression: out[b] = sum_{d,h} l3[b,d,h] * Wreg[d*256+h] + breg ----
  {
    int s = tid >> 5;
    int t32 = tid & 31;
    int h0 = t32 << 3;
    const float* f3 = (const float*)sBuf;
    float sum = 0.f;
    #pragma unroll
    for (int d = 0; d < 9; ++d) {
      const float* rp = f3 + (s * NLAGS + d) * F32STR + h0;
      float4v x0 = *(const float4v*)(rp);
      float4v x1 = *(const float4v*)(rp + 4);
      float4v r0 = *(const float4v*)(Wreg + d * 256 + h0);
      float4v r1 = *(const float4v*)(Wreg + d * 256 + h0 + 4);
      #pragma unroll
      for (int e = 0; e < 4; ++e) sum = fmaf(x0[e], sane(r0[e]), sum);
      #pragma unroll
      for (int e = 0; e < 4; ++e) sum = fmaf(x1[e], sane(r1[e]), sum);
    }
    sum += __shfl_down(sum, 16, 32);
    sum += __shfl_down(sum, 8, 32);
    sum += __shfl_down(sum, 4, 32);
    sum += __shfl_down(sum, 2, 32);
    sum += __shfl_down(sum, 1, 32);
    if (t32 == 0) out[s0 + s] = sum + sane(breg[0]);
  }
}

extern "C" void kernel_launch(void* const* d_in, const int* in_sizes, int n_in,
                              void* d_out, int out_size, void* d_ws, size_t ws_size,
                              hipStream_t stream) {
  const float* lags    = (const float*)d_in[0];
  const float* weather = (const float*)d_in[1];
  const float* Wl1     = (const float*)d_in[2];
  const float* bl1     = (const float*)d_in[3];
  const float* gbn     = (const float*)d_in[4];
  const float* bbn     = (const float*)d_in[5];
  const float* Wl2     = (const float*)d_in[6];
  const float* bl2     = (const float*)d_in[7];
  const float* Ww1     = (const float*)d_in[8];
  const float* bw1     = (const float*)d_in[9];
  const float* Ww2     = (const float*)d_in[10];
  const float* bw2     = (const float*)d_in[11];
  const float* Wm1     = (const float*)d_in[12];
  const float* bm1     = (const float*)d_in[13];
  const float* Wm2     = (const float*)d_in[14];
  const float* bm2     = (const float*)d_in[15];
  const float* Wreg    = (const float*)d_in[16];
  const float* breg    = (const float*)d_in[17];
  unsigned short* ws = (unsigned short*)d_ws;

  prep_kernel<<<1568, 256, 0, stream>>>(Wl2, Ww2, Wm1, Wm2, Ww1, ws);

  const int nblocks = 32768 / GSAMP;  // 2048
  fused_kernel<<<nblocks, NTHREADS, 0, stream>>>(
      lags, weather, Wl1, bl1, gbn, bbn, bl2, bw1, bw2, bm1, bm2,
      Wreg, breg, ws, (float*)d_out);
}